// Round 2
// baseline (968.221 us; speedup 1.0000x reference)
//
#include <hip/hip_runtime.h>

typedef unsigned short u16;
typedef unsigned int u32;
typedef unsigned long long u64;
typedef int   v4i  __attribute__((ext_vector_type(4)));
typedef short v8s  __attribute__((ext_vector_type(8)));
typedef float v2f  __attribute__((ext_vector_type(2)));
typedef float v16f __attribute__((ext_vector_type(16)));

#define B_ 256
#define T_ 120
#define E_ 256
#define H_ 1024
#define K_ 1280
#define LDH 1032    // 1024 + 8 pad (u16); row = 2064B, halves stay contiguous
#define LDX 264     // 256 + 8 pad

// ---- ws layout (bytes) ----
#define WS_WF   0                    // 10,485,760  (W fragments, bf16)
#define WS_X    10485760             // 15,728,640  (X (T,B,E) bf16)
#define WS_HS   26214400             // 62,914,560  (hs (T,B,H) bf16)
#define WS_BAR  89128960             // 4,096 (flags, 128 u32/group) + 96 (boot)

// HW_REG_XCC_ID = 20, offset 0, size 4  ->  simm16 = ((4-1)<<11) | (0<<6) | 20
#define GETREG_XCC_ID 6164

__device__ __forceinline__ u16 f2bf(float f) {
    union { float f; u32 u; } v; v.f = f;
    u32 r = v.u + 0x7fffu + ((v.u >> 16) & 1u);   // RNE
    return (u16)(r >> 16);
}
__device__ __forceinline__ float bf2f(u16 u) {
    union { u32 u; float f; } v; v.u = ((u32)u) << 16; return v.f;
}
__device__ __forceinline__ float fsig(float x) {
    float t = __builtin_amdgcn_exp2f(-1.44269504f * x);
    return __builtin_amdgcn_rcpf(1.0f + t);
}
__device__ __forceinline__ float ftanh_(float x) {
    float xc = fminf(8.0f, fmaxf(-8.0f, x));
    float t = __builtin_amdgcn_exp2f(2.88539008f * xc);
    return (t - 1.0f) * __builtin_amdgcn_rcpf(t + 1.0f);
}
__device__ __forceinline__ void gl_lds16(const void* g, void* l) {
    __builtin_amdgcn_global_load_lds(
        (const __attribute__((address_space(1))) void*)g,
        (__attribute__((address_space(3))) void*)l, 16, 0, 0);
}
// L2-read poll: sc0 bypasses L1 and reads the XCD-local L2 (where no-sc-bit
// atomics execute). Does NOT go out to the Infinity Cache.
__device__ __forceinline__ u32 l2_poll(const u32* p) {
    u64 pa = (u64)p;
    u32 v;
    asm volatile("global_load_dword %0, %1, off sc0\n\ts_waitcnt vmcnt(0)"
                 : "=v"(v) : "v"(pa) : "memory");
    return v;
}

// ---------------- P1: W (1280,4096) f32 -> bf16 32x32x16 B-fragments ----------------
__global__ void prep_w(const float* __restrict__ W, u16* __restrict__ Wf) {
    __shared__ u16 tile[32 * 136];        // [col 0..31][localk 0..127 + 8 pad]
    int bid = blockIdx.x;
    int cid = bid / 5, fo = bid % 5;
    int kh  = cid & 1, g = (cid >> 1) & 3, nc = cid >> 3;
    int colbase = g * 1024 + nc * 32;
    int tid = threadIdx.x;
    int c = tid & 31, r = tid >> 5;       // r 0..7

#pragma unroll
    for (int fl = 0; fl < 8; ++fl) {
        int k0 = (2 * (fo * 8 + fl) + kh) * 16;
#pragma unroll
        for (int rr = 0; rr < 2; ++rr) {
            int row = r + rr * 8;         // 0..15
            float v = W[(size_t)(k0 + row) * 4096 + colbase + c];
            tile[c * 136 + fl * 16 + row] = f2bf(v);
        }
    }
    __syncthreads();

    int lane = tid & 63;
#pragma unroll
    for (int pass = 0; pass < 2; ++pass) {
        int fl = (tid >> 6) + pass * 4;
        v4i o = *(const v4i*)&tile[(lane & 31) * 136 + fl * 16 + ((lane >> 5) << 3)];
        *(v4i*)(Wf + (((size_t)(cid * 40 + fo * 8 + fl)) << 9) + lane * 8) = o;
    }
}

// ---------------- P2: embedding gather -> X (T,B,E) bf16 ----------------
__global__ void prep_x(const int* __restrict__ tokens, const float* __restrict__ emb,
                       u16* __restrict__ X) {
    int v   = blockIdx.x * 256 + threadIdx.x;     // < 983040
    int e8  = v & 31;
    int row = v >> 5;                             // t*256 + b
    int t = row >> 8, b = row & 255;
    int tok = tokens[b * T_ + t];
    const float* src = emb + (size_t)tok * E_ + e8 * 8;
    u16 o[8];
#pragma unroll
    for (int j = 0; j < 8; ++j) o[j] = f2bf(src[j]);
    *(v4i*)(X + (size_t)row * E_ + e8 * 8) = *(v4i*)o;
}

// ---------------- main persistent LSTM kernel ----------------
// 256 blocks x 512 threads. Block (mchunk=bid&7, nc=bid>>3). Wave (g=wv>>1,
// khalf=wv&1): 32x32 gate tile, K-parity split. W pinned in registers.
//
// Exchange-mode bootstrap (deadlock-proof):
//  A) publish s_getreg(HW_REG_XCC_ID) into boot[mchunk] via AGENT fetch_or
//     (IC-coherent single copy), arrive on boot[16].
//  B) wait arrivals==256 (agent), hw_ok = popcount(group mask)==1.
//  C) if hw_ok: BOUNDED rehearsal of the L2-local mechanism itself —
//     workgroup-scope global_atomic_add on boot[8+mchunk] + sc0 poll.
//     Timeout => mechanism unproven => vote no.
//  D) unanimous global vote on boot[17] (agent). fast iff all 256 say yes.
// Slow path == baseline agent-scope protocol exactly. Fast path keeps the
// h store / flag add / flag poll inside the XCD's L2 (no IC round trips).
// Flags strided 128 u32/group: each group's flag words own whole 128B lines.
__global__ __launch_bounds__(512, 2) void lstm_main(
    const u16* __restrict__ Wf, const u16* __restrict__ X,
    const float* __restrict__ b_lstm, u16* __restrict__ hs,
    u32* __restrict__ bar, u32* __restrict__ boot) {

    __shared__ u16  hbuf[32 * LDH];          // 66,048 B
    __shared__ u16  xbuf[32 * LDX];          // 16,896 B
    __shared__ float gates[2 * 4 * 32 * 34]; // 34,816 B
    __shared__ float bias[128];
    __shared__ u32 fastflag;

    const int tid   = threadIdx.x;
    const int lane  = tid & 63;
    const int wv    = tid >> 6;
    const int g     = wv >> 1;
    const int khalf = wv & 1;
    const int bid   = blockIdx.x;
    const int mchunk = bid & 7;
    const int nc    = bid >> 3;
    const int m0    = mchunk << 5;

    // ---- Phase A: publish XCD id (agent scope, IC-coherent) ----
    if (tid == 0) {
        u32 xcd = __builtin_amdgcn_s_getreg(GETREG_XCC_ID) & 15u;
        __hip_atomic_fetch_or(&boot[mchunk], 1u << xcd,
                              __ATOMIC_RELAXED, __HIP_MEMORY_SCOPE_AGENT);
        asm volatile("s_waitcnt vmcnt(0)" ::: "memory");   // or visible before arrive
        __hip_atomic_fetch_add(&boot[16], 1u,
                               __ATOMIC_RELAXED, __HIP_MEMORY_SCOPE_AGENT);
    }

    if (tid < 128) bias[tid] = b_lstm[(tid >> 5) * H_ + (nc << 5) + (tid & 31)];

    // ---- resident W fragments: 40 x v8s, pinned ----
    v8s Wr[40];
    {
        const int cid = nc * 8 + g * 2 + khalf;
        const v4i* wsrc = (const v4i*)(Wf + (size_t)cid * 40 * 512);
#pragma unroll
        for (int f = 0; f < 40; ++f)
            Wr[f] = __builtin_bit_cast(v8s, wsrc[f * 64 + lane]);
    }
#pragma unroll
    for (int f = 0; f < 40; ++f) asm volatile("" : "+v"(Wr[f]));

    // ---- stage X_0 ----
    {
        const v4i* xs = (const v4i*)(X + (size_t)m0 * E_);
#pragma unroll
        for (int i = 0; i < 2; ++i) {
            int idx = tid + i * 512;
            int r = idx >> 5, c8 = idx & 31;
            *(v4i*)&xbuf[r * LDX + c8 * 8] = xs[r * 32 + c8];
        }
    }

    // ---- Phases B/C/D: resolve exchange mode ----
    if (tid == 0) {
        // B: wait for all 256 publishes, read own group's mask
        while (__hip_atomic_load(&boot[16], __ATOMIC_RELAXED,
                                 __HIP_MEMORY_SCOPE_AGENT) < 256u)
            __builtin_amdgcn_s_sleep(1);
        u32 msk = __hip_atomic_load(&boot[mchunk], __ATOMIC_RELAXED,
                                    __HIP_MEMORY_SCOPE_AGENT);
        u32 hw_ok = (msk != 0u && (msk & (msk - 1u)) == 0u) ? 1u : 0u;

        // C: bounded rehearsal of the exact L2-local fast mechanism
        u32 trial_ok = 0u;
        if (hw_ok) {
            __hip_atomic_fetch_add(&boot[8 + mchunk], 1u,
                                   __ATOMIC_RELAXED, __HIP_MEMORY_SCOPE_WORKGROUP);
            for (int it = 0; it < 4000; ++it) {
                if (l2_poll(&boot[8 + mchunk]) >= 32u) { trial_ok = 1u; break; }
                __builtin_amdgcn_s_sleep(1);
            }
        }

        // D: unanimous global vote (agent)
        __hip_atomic_fetch_add(&boot[17], (1u << 16) | (hw_ok & trial_ok),
                               __ATOMIC_RELAXED, __HIP_MEMORY_SCOPE_AGENT);
        u32 w;
        for (;;) {
            w = __hip_atomic_load(&boot[17], __ATOMIC_RELAXED,
                                  __HIP_MEMORY_SCOPE_AGENT);
            if ((w >> 16) >= 256u) break;
            __builtin_amdgcn_s_sleep(1);
        }
        fastflag = ((w & 0xFFFFu) == 256u) ? 1u : 0u;
    }
    __syncthreads();
    const bool fast = (fastflag != 0u);

    const u16* Ax = &xbuf[(lane & 31) * LDX + ((lane >> 5) << 3)];
    const u16* Ah = &hbuf[(lane & 31) * LDH + ((lane >> 5) << 3)];

    // ---- x-part MFMA for t=0 ----
    v16f acc = {0,0,0,0,0,0,0,0,0,0,0,0,0,0,0,0};
#pragma unroll
    for (int f = 0; f < 8; ++f) {
        v8s a = *(const v8s*)(Ax + (2 * f + khalf) * 16);
        acc = __builtin_amdgcn_mfma_f32_32x32x16_bf16(a, Wr[f], acc, 0, 0, 0);
    }

    float cst[2] = {0.f, 0.f};
    const int cm  = tid >> 4;
    const int cn2 = (tid & 15) << 1;
    u32* hs32 = (u32*)hs;

    for (int t = 0; t < T_; ++t) {
        if (t > 0) {
            // ---- wait for h_{t-1} flag (usually already set: hidden by x-MFMAs) ----
            if (tid == 0) {
                u32* p = &bar[mchunk * 128 + (t - 1)];
                if (fast) {
                    while (l2_poll(p) < 32u) __builtin_amdgcn_s_sleep(1);
                } else {
                    while (__hip_atomic_load(p, __ATOMIC_RELAXED,
                                             __HIP_MEMORY_SCOPE_AGENT) < 32u)
                        __builtin_amdgcn_s_sleep(1);
                }
            }
            __syncthreads();
            // ---- issue async h loads: wave wv -> rows [wv*4, wv*4+4), halves 0,1 ----
            {
                const u16* srcb = hs + ((size_t)(t - 1) * B_ + m0) * H_;
                int r0 = wv << 2;
#pragma unroll
                for (int half = 0; half < 2; ++half)
#pragma unroll
                    for (int i = 0; i < 4; ++i) {
                        int r = r0 + i;
                        gl_lds16(srcb + (size_t)r * H_ + half * 512 + lane * 8,
                                 &hbuf[r * LDH + half * 512]);
                    }
            }
            // ---- chunk A: cols [0,512) ready after own-wave vmcnt(4) + barrier ----
            asm volatile("s_waitcnt vmcnt(4)\n\ts_barrier" ::: "memory");
#pragma unroll
            for (int f = 8; f < 24; ++f) {
                v8s a = *(const v8s*)(Ah + ((2 * f + khalf) * 16 - 256));
                acc = __builtin_amdgcn_mfma_f32_32x32x16_bf16(a, Wr[f], acc, 0, 0, 0);
            }
            // ---- chunk B: cols [512,1024) ----
            asm volatile("s_waitcnt vmcnt(0)\n\ts_barrier" ::: "memory");
#pragma unroll
            for (int f = 24; f < 40; ++f) {
                v8s a = *(const v8s*)(Ah + ((2 * f + khalf) * 16 - 256));
                acc = __builtin_amdgcn_mfma_f32_32x32x16_bf16(a, Wr[f], acc, 0, 0, 0);
            }
        }

        // ---- partials -> LDS: C/D col=lane&31, row=(reg&3)+8*(reg>>2)+4*(lane>>5) ----
        {
            float* gb = &gates[((khalf << 2) + g) * 1088];
            int col = lane & 31, rq = (lane >> 5) << 2;
#pragma unroll
            for (int reg = 0; reg < 16; ++reg) {
                int row = (reg & 3) + ((reg >> 2) << 3) + rq;
                gb[row * 34 + col] = acc[reg];
            }
        }
        __syncthreads();

        // ---- prefetch X_{t+1} (issues early; overlaps cell transcendentals) ----
        if (t + 1 < T_) {
            const v4i* xs = (const v4i*)(X + ((size_t)(t + 1) * B_ + m0) * E_);
#pragma unroll
            for (int i = 0; i < 2; ++i) {
                int idx = tid + i * 512;
                int r = idx >> 5, c8 = idx & 31;
                *(v4i*)&xbuf[r * LDX + c8 * 8] = xs[r * 32 + c8];
            }
        }

        // ---- cell math: sum K-halves, bias, activations ----
        u32 hpack = 0;
        {
            v2f zz[4];
#pragma unroll
            for (int gg = 0; gg < 4; ++gg) {
                v2f a = *(const v2f*)&gates[gg * 1088 + cm * 34 + cn2];
                v2f b = *(const v2f*)&gates[(4 + gg) * 1088 + cm * 34 + cn2];
                zz[gg].x = a.x + b.x; zz[gg].y = a.y + b.y;
            }
#pragma unroll
            for (int q = 0; q < 2; ++q) {
                int n = cn2 + q;
                float ip = zz[0][q] + bias[n];
                float jp = zz[1][q] + bias[32 + n];
                float fp = zz[2][q] + bias[64 + n] + 1.0f;
                float op = zz[3][q] + bias[96 + n];
                float cc = fsig(fp) * cst[q] + fsig(ip) * ftanh_(jp);
                cst[q] = cc;
                hpack |= ((u32)f2bf(fsig(op) * ftanh_(cc))) << (16 * q);
            }
        }
        {
            size_t oidx = ((size_t)t * B_ + m0 + cm) * 512 + (nc << 4) + (tid & 15);
            if (fast) {
                hs32[oidx] = hpack;      // plain writeback store: stays in XCD L2
            } else {
                __hip_atomic_store(&hs32[oidx], hpack, __ATOMIC_RELAXED,
                                   __HIP_MEMORY_SCOPE_AGENT);
            }
        }

        if (t + 1 < T_) {
            // ---- release: each wave drains its own VM ops, barrier, then flag ----
            asm volatile("s_waitcnt vmcnt(0)" ::: "memory");
            __syncthreads();
            if (tid == 0) {
                if (fast)
                    __hip_atomic_fetch_add(&bar[mchunk * 128 + t], 1u,
                                           __ATOMIC_RELAXED, __HIP_MEMORY_SCOPE_WORKGROUP);
                else
                    __hip_atomic_fetch_add(&bar[mchunk * 128 + t], 1u,
                                           __ATOMIC_RELAXED, __HIP_MEMORY_SCOPE_AGENT);
            }
            // ---- x-part MFMA for t+1 (hides handshake latency) ----
#pragma unroll
            for (int reg = 0; reg < 16; ++reg) acc[reg] = 0.f;
#pragma unroll
            for (int f = 0; f < 8; ++f) {
                v8s a = *(const v8s*)(Ax + (2 * f + khalf) * 16);
                acc = __builtin_amdgcn_mfma_f32_32x32x16_bf16(a, Wr[f], acc, 0, 0, 0);
            }
        }
    }
}

// ---------------- P3: preds = hs @ U + b2 (64 rows/block; U staged once) ----------------
__global__ void proj_kernel(const u16* __restrict__ hs, const float* __restrict__ U,
                            const float* __restrict__ b2, float* __restrict__ out) {
    __shared__ float Ul[H_ * 5];
    int tid = threadIdx.x;
    for (int i = tid; i < H_ * 5; i += 256) Ul[i] = U[i];
    __syncthreads();
    int wv = tid >> 6, lane = tid & 63;
#pragma unroll 1
    for (int i = 0; i < 16; ++i) {
        int row = blockIdx.x * 64 + wv * 16 + i;   // t*256 + b, < 30720
        int t = row >> 8, b = row & 255;
        const v4i* hp = (const v4i*)(hs + (size_t)row * H_);
        float p[5] = {0.f, 0.f, 0.f, 0.f, 0.f};
#pragma unroll
        for (int half = 0; half < 2; ++half) {
            v4i hv = hp[lane * 2 + half];
            u16 us[8];
            *(v4i*)us = hv;
#pragma unroll
            for (int j = 0; j < 8; ++j) {
                float hf = bf2f(us[j]);
                int k = lane * 16 + half * 8 + j;
#pragma unroll
                for (int c = 0; c < 5; ++c) p[c] += hf * Ul[k * 5 + c];
            }
        }
#pragma unroll
        for (int c = 0; c < 5; ++c)
            for (int off = 32; off > 0; off >>= 1)
                p[c] += __shfl_down(p[c], off, 64);
        if (lane == 0) {
#pragma unroll
            for (int c = 0; c < 5; ++c)
                out[((size_t)b * T_ + t) * 5 + c] = p[c] + b2[c];
        }
    }
}

extern "C" void kernel_launch(void* const* d_in, const int* in_sizes, int n_in,
                              void* d_out, int out_size, void* d_ws, size_t ws_size,
                              hipStream_t stream) {
    const int*   tokens = (const int*)d_in[0];
    const float* emb    = (const float*)d_in[1];
    const float* W      = (const float*)d_in[2];
    const float* b_l    = (const float*)d_in[3];
    const float* U      = (const float*)d_in[4];
    const float* b2     = (const float*)d_in[5];
    float* out = (float*)d_out;

    char* ws = (char*)d_ws;
    u16* Wf  = (u16*)(ws + WS_WF);
    u16* X   = (u16*)(ws + WS_X);
    u16* hs  = (u16*)(ws + WS_HS);

    // flags: 8 groups x 128 u32 (line-isolated) = 4096 B; boot: 24 u32 = 96 B.
    // Prefer workspace; if ws is exactly tight, fall back to d_out head (dead
    // space during lstm_main — proj_kernel overwrites all of out afterwards).
    u32* bar;
    if (ws_size >= (size_t)WS_BAR + 4096 + 96) bar = (u32*)(ws + WS_BAR);
    else                                       bar = (u32*)d_out;
    u32* boot = bar + 1024;

    hipMemsetAsync(bar, 0, 4096 + 96, stream);
    prep_w<<<1280, 256, 0, stream>>>(W, Wf);
    prep_x<<<3840, 256, 0, stream>>>(tokens, emb, X);
    lstm_main<<<256, 512, 0, stream>>>(Wf, X, b_l, hs, bar, boot);
    proj_kernel<<<480, 256, 0, stream>>>(hs, U, b2, out);
}

// Round 3
// 630.575 us; speedup vs baseline: 1.5355x; 1.5355x over previous
//
#include <hip/hip_runtime.h>

typedef unsigned short u16;
typedef unsigned int u32;
typedef unsigned long long u64;
typedef int   v4i  __attribute__((ext_vector_type(4)));
typedef short v8s  __attribute__((ext_vector_type(8)));
typedef float v2f  __attribute__((ext_vector_type(2)));
typedef float v16f __attribute__((ext_vector_type(16)));

#define B_ 256
#define T_ 120
#define E_ 256
#define H_ 1024
#define K_ 1280
#define LDH 1032    // 1024 + 8 pad (u16); row = 2064B, halves stay contiguous
#define LDX 264     // 256 + 8 pad

// ---- ws layout (bytes) ----
#define WS_WF   0                    // 10,485,760  (W fragments, bf16)
#define WS_X    10485760             // 15,728,640  (X (T,B,E) bf16)
#define WS_HS   26214400             // 62,914,560  (hs (T,B,H) bf16)
#define WS_BAR  89128960             // 4,096 flags + 1,152 boot

// HW_REG_XCC_ID = 20, offset 0, size 4  ->  simm16 = ((4-1)<<11) | (0<<6) | 20
#define GETREG_XCC_ID 6164

__device__ __forceinline__ u16 f2bf(float f) {
    union { float f; u32 u; } v; v.f = f;
    u32 r = v.u + 0x7fffu + ((v.u >> 16) & 1u);   // RNE
    return (u16)(r >> 16);
}
__device__ __forceinline__ float bf2f(u16 u) {
    union { u32 u; float f; } v; v.u = ((u32)u) << 16; return v.f;
}
__device__ __forceinline__ float fsig(float x) {
    float t = __builtin_amdgcn_exp2f(-1.44269504f * x);
    return __builtin_amdgcn_rcpf(1.0f + t);
}
__device__ __forceinline__ float ftanh_(float x) {
    float xc = fminf(8.0f, fmaxf(-8.0f, x));
    float t = __builtin_amdgcn_exp2f(2.88539008f * xc);
    return (t - 1.0f) * __builtin_amdgcn_rcpf(t + 1.0f);
}
__device__ __forceinline__ void gl_lds16(const void* g, void* l) {
    __builtin_amdgcn_global_load_lds(
        (const __attribute__((address_space(1))) void*)g,
        (__attribute__((address_space(3))) void*)l, 16, 0, 0);
}
// Stale-proof L2 poll: atomic add of 0 with returned old value. Atomics
// execute at the L2 coherency point — can never be served from a stale L1
// line (round-2 failure mode). Raw asm so LLVM can't fold it into a load.
__device__ __forceinline__ u32 poll_atomic(u32* p) {
    u64 pa = (u64)p;
    u32 zero = 0, v;
    asm volatile("global_atomic_add %0, %1, %2, off sc0\n\ts_waitcnt vmcnt(0)"
                 : "=v"(v) : "v"(pa), "v"(zero) : "memory");
    return v;
}

// ---------------- P1: W (1280,4096) f32 -> bf16 32x32x16 B-fragments ----------------
__global__ void prep_w(const float* __restrict__ W, u16* __restrict__ Wf) {
    __shared__ u16 tile[32 * 136];        // [col 0..31][localk 0..127 + 8 pad]
    int bid = blockIdx.x;
    int cid = bid / 5, fo = bid % 5;
    int kh  = cid & 1, g = (cid >> 1) & 3, nc = cid >> 3;
    int colbase = g * 1024 + nc * 32;
    int tid = threadIdx.x;
    int c = tid & 31, r = tid >> 5;       // r 0..7

#pragma unroll
    for (int fl = 0; fl < 8; ++fl) {
        int k0 = (2 * (fo * 8 + fl) + kh) * 16;
#pragma unroll
        for (int rr = 0; rr < 2; ++rr) {
            int row = r + rr * 8;         // 0..15
            float v = W[(size_t)(k0 + row) * 4096 + colbase + c];
            tile[c * 136 + fl * 16 + row] = f2bf(v);
        }
    }
    __syncthreads();

    int lane = tid & 63;
#pragma unroll
    for (int pass = 0; pass < 2; ++pass) {
        int fl = (tid >> 6) + pass * 4;
        v4i o = *(const v4i*)&tile[(lane & 31) * 136 + fl * 16 + ((lane >> 5) << 3)];
        *(v4i*)(Wf + (((size_t)(cid * 40 + fo * 8 + fl)) << 9) + lane * 8) = o;
    }
}

// ---------------- P2: embedding gather -> X (T,B,E) bf16 ----------------
__global__ void prep_x(const int* __restrict__ tokens, const float* __restrict__ emb,
                       u16* __restrict__ X) {
    int v   = blockIdx.x * 256 + threadIdx.x;     // < 983040
    int e8  = v & 31;
    int row = v >> 5;                             // t*256 + b
    int t = row >> 8, b = row & 255;
    int tok = tokens[b * T_ + t];
    const float* src = emb + (size_t)tok * E_ + e8 * 8;
    u16 o[8];
#pragma unroll
    for (int j = 0; j < 8; ++j) o[j] = f2bf(src[j]);
    *(v4i*)(X + (size_t)row * E_ + e8 * 8) = *(v4i*)o;
}

// ---------------- main persistent LSTM kernel ----------------
// 256 blocks x 512 threads. Block (mchunk=bid&7, nc=bid>>3). Wave (g=wv>>1,
// khalf=wv&1): 32x32 gate tile, K-parity split. W pinned in registers.
//
// Exchange-mode bootstrap (deadlock-proof, stale-proof):
//  A) publish s_getreg(HW_REG_XCC_ID) into boot[mchunk] via AGENT fetch_or,
//     arrive on boot[8].
//  B) wait arrivals==256 (agent), hw_ok = popcount(group mask)==1.
//  C) if hw_ok: BOUNDED rehearsal of the L2-local mechanism — workgroup-scope
//     global_atomic_add on a PRIVATE 128B line + atomic-returning poll
//     (poll_atomic; round 2's plain sc0 load poll read stale L1 and burned
//     the timeout). Timeout (1000 it) => vote no.
//  D) unanimous global vote on boot[9] (agent). fast iff all 256 say yes.
//     !fast => 2MB marker stores (WRITE_SIZE diagnosis channel).
// Slow path == baseline agent-scope protocol exactly. Fast path keeps the
// h store / flag add / flag poll inside the XCD's L2 (no IC round trips).
// boot line map: words 0..9 agent-only (one 128B line); trial counters at
// word 32+32*m (one private line per group) — L2-local and agent atomics
// never share a line (round-2 writeback-race hazard).
__global__ __launch_bounds__(512, 2) void lstm_main(
    const u16* __restrict__ Wf, const u16* __restrict__ X,
    const float* __restrict__ b_lstm, u16* __restrict__ hs,
    u32* __restrict__ bar, u32* __restrict__ boot) {

    __shared__ u16  hbuf[32 * LDH];          // 66,048 B
    __shared__ u16  xbuf[32 * LDX];          // 16,896 B
    __shared__ float gates[2 * 4 * 32 * 34]; // 34,816 B
    __shared__ float bias[128];
    __shared__ u32 fastflag;

    const int tid   = threadIdx.x;
    const int lane  = tid & 63;
    const int wv    = tid >> 6;
    const int g     = wv >> 1;
    const int khalf = wv & 1;
    const int bid   = blockIdx.x;
    const int mchunk = bid & 7;
    const int nc    = bid >> 3;
    const int m0    = mchunk << 5;

    // ---- Phase A: publish XCD id (agent scope, IC-coherent) ----
    if (tid == 0) {
        u32 xcd = __builtin_amdgcn_s_getreg(GETREG_XCC_ID) & 15u;
        __hip_atomic_fetch_or(&boot[mchunk], 1u << xcd,
                              __ATOMIC_RELAXED, __HIP_MEMORY_SCOPE_AGENT);
        asm volatile("s_waitcnt vmcnt(0)" ::: "memory");   // or visible before arrive
        __hip_atomic_fetch_add(&boot[8], 1u,
                               __ATOMIC_RELAXED, __HIP_MEMORY_SCOPE_AGENT);
    }

    if (tid < 128) bias[tid] = b_lstm[(tid >> 5) * H_ + (nc << 5) + (tid & 31)];

    // ---- resident W fragments: 40 x v8s, pinned ----
    v8s Wr[40];
    {
        const int cid = nc * 8 + g * 2 + khalf;
        const v4i* wsrc = (const v4i*)(Wf + (size_t)cid * 40 * 512);
#pragma unroll
        for (int f = 0; f < 40; ++f)
            Wr[f] = __builtin_bit_cast(v8s, wsrc[f * 64 + lane]);
    }
#pragma unroll
    for (int f = 0; f < 40; ++f) asm volatile("" : "+v"(Wr[f]));

    // ---- stage X_0 ----
    {
        const v4i* xs = (const v4i*)(X + (size_t)m0 * E_);
#pragma unroll
        for (int i = 0; i < 2; ++i) {
            int idx = tid + i * 512;
            int r = idx >> 5, c8 = idx & 31;
            *(v4i*)&xbuf[r * LDX + c8 * 8] = xs[r * 32 + c8];
        }
    }

    // ---- Phases B/C/D: resolve exchange mode ----
    if (tid == 0) {
        // B: wait for all 256 publishes, read own group's mask
        while (__hip_atomic_load(&boot[8], __ATOMIC_RELAXED,
                                 __HIP_MEMORY_SCOPE_AGENT) < 256u)
            __builtin_amdgcn_s_sleep(1);
        u32 msk = __hip_atomic_load(&boot[mchunk], __ATOMIC_RELAXED,
                                    __HIP_MEMORY_SCOPE_AGENT);
        u32 hw_ok = (msk != 0u && (msk & (msk - 1u)) == 0u) ? 1u : 0u;

        // C: bounded rehearsal of the exact L2-local fast mechanism
        u32 trial_ok = 0u;
        if (hw_ok) {
            u32* tc = &boot[32 + 32 * mchunk];   // private 128B line per group
            __hip_atomic_fetch_add(tc, 1u,
                                   __ATOMIC_RELAXED, __HIP_MEMORY_SCOPE_WORKGROUP);
            for (int it = 0; it < 1000; ++it) {
                if (poll_atomic(tc) >= 32u) { trial_ok = 1u; break; }
                __builtin_amdgcn_s_sleep(1);
            }
        }

        // D: unanimous global vote (agent)
        __hip_atomic_fetch_add(&boot[9], (1u << 16) | (hw_ok & trial_ok),
                               __ATOMIC_RELAXED, __HIP_MEMORY_SCOPE_AGENT);
        u32 w;
        for (;;) {
            w = __hip_atomic_load(&boot[9], __ATOMIC_RELAXED,
                                  __HIP_MEMORY_SCOPE_AGENT);
            if ((w >> 16) >= 256u) break;
            __builtin_amdgcn_s_sleep(1);
        }
        fastflag = ((w & 0xFFFFu) == 256u) ? 1u : 0u;
    }
    __syncthreads();
    const bool fast = (fastflag != 0u);

    // ---- vote-no marker: +2MB WRITE_SIZE so the profile reveals the mode.
    // Sink = hs[t=116..119] region: rewritten by real h (flag-ordered, IC
    // side) long after these agent stores drain; read only after rewrite.
    if (!fast) {
        u32* mk = (u32*)hs + 15204352 + (bid << 11) + (tid << 2);
#pragma unroll
        for (int j = 0; j < 4; ++j)
            __hip_atomic_store(mk + j, 0x7e7e7e7eu,
                               __ATOMIC_RELAXED, __HIP_MEMORY_SCOPE_AGENT);
    }

    const u16* Ax = &xbuf[(lane & 31) * LDX + ((lane >> 5) << 3)];
    const u16* Ah = &hbuf[(lane & 31) * LDH + ((lane >> 5) << 3)];

    // ---- x-part MFMA for t=0 ----
    v16f acc = {0,0,0,0,0,0,0,0,0,0,0,0,0,0,0,0};
#pragma unroll
    for (int f = 0; f < 8; ++f) {
        v8s a = *(const v8s*)(Ax + (2 * f + khalf) * 16);
        acc = __builtin_amdgcn_mfma_f32_32x32x16_bf16(a, Wr[f], acc, 0, 0, 0);
    }

    float cst[2] = {0.f, 0.f};
    const int cm  = tid >> 4;
    const int cn2 = (tid & 15) << 1;
    u32* hs32 = (u32*)hs;

    for (int t = 0; t < T_; ++t) {
        if (t > 0) {
            // ---- wait for h_{t-1} flag (usually already set: hidden by x-MFMAs) ----
            if (tid == 0) {
                u32* p = &bar[mchunk * 128 + (t - 1)];
                if (fast) {
                    while (poll_atomic(p) < 32u) __builtin_amdgcn_s_sleep(1);
                } else {
                    while (__hip_atomic_load(p, __ATOMIC_RELAXED,
                                             __HIP_MEMORY_SCOPE_AGENT) < 32u)
                        __builtin_amdgcn_s_sleep(1);
                }
            }
            __syncthreads();
            // ---- issue async h loads: wave wv -> rows [wv*4, wv*4+4), halves 0,1 ----
            {
                const u16* srcb = hs + ((size_t)(t - 1) * B_ + m0) * H_;
                int r0 = wv << 2;
#pragma unroll
                for (int half = 0; half < 2; ++half)
#pragma unroll
                    for (int i = 0; i < 4; ++i) {
                        int r = r0 + i;
                        gl_lds16(srcb + (size_t)r * H_ + half * 512 + lane * 8,
                                 &hbuf[r * LDH + half * 512]);
                    }
            }
            // ---- chunk A: cols [0,512) ready after own-wave vmcnt(4) + barrier ----
            asm volatile("s_waitcnt vmcnt(4)\n\ts_barrier" ::: "memory");
#pragma unroll
            for (int f = 8; f < 24; ++f) {
                v8s a = *(const v8s*)(Ah + ((2 * f + khalf) * 16 - 256));
                acc = __builtin_amdgcn_mfma_f32_32x32x16_bf16(a, Wr[f], acc, 0, 0, 0);
            }
            // ---- chunk B: cols [512,1024) ----
            asm volatile("s_waitcnt vmcnt(0)\n\ts_barrier" ::: "memory");
#pragma unroll
            for (int f = 24; f < 40; ++f) {
                v8s a = *(const v8s*)(Ah + ((2 * f + khalf) * 16 - 256));
                acc = __builtin_amdgcn_mfma_f32_32x32x16_bf16(a, Wr[f], acc, 0, 0, 0);
            }
        }

        // ---- partials -> LDS: C/D col=lane&31, row=(reg&3)+8*(reg>>2)+4*(lane>>5) ----
        {
            float* gb = &gates[((khalf << 2) + g) * 1088];
            int col = lane & 31, rq = (lane >> 5) << 2;
#pragma unroll
            for (int reg = 0; reg < 16; ++reg) {
                int row = (reg & 3) + ((reg >> 2) << 3) + rq;
                gb[row * 34 + col] = acc[reg];
            }
        }
        __syncthreads();

        // ---- prefetch X_{t+1} (issues early; overlaps cell transcendentals) ----
        if (t + 1 < T_) {
            const v4i* xs = (const v4i*)(X + ((size_t)(t + 1) * B_ + m0) * E_);
#pragma unroll
            for (int i = 0; i < 2; ++i) {
                int idx = tid + i * 512;
                int r = idx >> 5, c8 = idx & 31;
                *(v4i*)&xbuf[r * LDX + c8 * 8] = xs[r * 32 + c8];
            }
        }

        // ---- cell math: sum K-halves, bias, activations ----
        u32 hpack = 0;
        {
            v2f zz[4];
#pragma unroll
            for (int gg = 0; gg < 4; ++gg) {
                v2f a = *(const v2f*)&gates[gg * 1088 + cm * 34 + cn2];
                v2f b = *(const v2f*)&gates[(4 + gg) * 1088 + cm * 34 + cn2];
                zz[gg].x = a.x + b.x; zz[gg].y = a.y + b.y;
            }
#pragma unroll
            for (int q = 0; q < 2; ++q) {
                int n = cn2 + q;
                float ip = zz[0][q] + bias[n];
                float jp = zz[1][q] + bias[32 + n];
                float fp = zz[2][q] + bias[64 + n] + 1.0f;
                float op = zz[3][q] + bias[96 + n];
                float cc = fsig(fp) * cst[q] + fsig(ip) * ftanh_(jp);
                cst[q] = cc;
                hpack |= ((u32)f2bf(fsig(op) * ftanh_(cc))) << (16 * q);
            }
        }
        {
            size_t oidx = ((size_t)t * B_ + m0 + cm) * 512 + (nc << 4) + (tid & 15);
            if (fast) {
                hs32[oidx] = hpack;      // plain writeback store: stays in XCD L2
            } else {
                __hip_atomic_store(&hs32[oidx], hpack, __ATOMIC_RELAXED,
                                   __HIP_MEMORY_SCOPE_AGENT);
            }
        }

        if (t + 1 < T_) {
            // ---- release: each wave drains its own VM ops, barrier, then flag ----
            asm volatile("s_waitcnt vmcnt(0)" ::: "memory");
            __syncthreads();
            if (tid == 0) {
                if (fast)
                    __hip_atomic_fetch_add(&bar[mchunk * 128 + t], 1u,
                                           __ATOMIC_RELAXED, __HIP_MEMORY_SCOPE_WORKGROUP);
                else
                    __hip_atomic_fetch_add(&bar[mchunk * 128 + t], 1u,
                                           __ATOMIC_RELAXED, __HIP_MEMORY_SCOPE_AGENT);
            }
            // ---- x-part MFMA for t+1 (hides handshake latency) ----
#pragma unroll
            for (int reg = 0; reg < 16; ++reg) acc[reg] = 0.f;
#pragma unroll
            for (int f = 0; f < 8; ++f) {
                v8s a = *(const v8s*)(Ax + (2 * f + khalf) * 16);
                acc = __builtin_amdgcn_mfma_f32_32x32x16_bf16(a, Wr[f], acc, 0, 0, 0);
            }
        }
    }
}

// ---------------- P3: preds = hs @ U + b2 (64 rows/block; U staged once) ----------------
__global__ void proj_kernel(const u16* __restrict__ hs, const float* __restrict__ U,
                            const float* __restrict__ b2, float* __restrict__ out) {
    __shared__ float Ul[H_ * 5];
    int tid = threadIdx.x;
    for (int i = tid; i < H_ * 5; i += 256) Ul[i] = U[i];
    __syncthreads();
    int wv = tid >> 6, lane = tid & 63;
#pragma unroll 1
    for (int i = 0; i < 16; ++i) {
        int row = blockIdx.x * 64 + wv * 16 + i;   // t*256 + b, < 30720
        int t = row >> 8, b = row & 255;
        const v4i* hp = (const v4i*)(hs + (size_t)row * H_);
        float p[5] = {0.f, 0.f, 0.f, 0.f, 0.f};
#pragma unroll
        for (int half = 0; half < 2; ++half) {
            v4i hv = hp[lane * 2 + half];
            u16 us[8];
            *(v4i*)us = hv;
#pragma unroll
            for (int j = 0; j < 8; ++j) {
                float hf = bf2f(us[j]);
                int k = lane * 16 + half * 8 + j;
#pragma unroll
                for (int c = 0; c < 5; ++c) p[c] += hf * Ul[k * 5 + c];
            }
        }
#pragma unroll
        for (int c = 0; c < 5; ++c)
            for (int off = 32; off > 0; off >>= 1)
                p[c] += __shfl_down(p[c], off, 64);
        if (lane == 0) {
#pragma unroll
            for (int c = 0; c < 5; ++c)
                out[((size_t)b * T_ + t) * 5 + c] = p[c] + b2[c];
        }
    }
}

extern "C" void kernel_launch(void* const* d_in, const int* in_sizes, int n_in,
                              void* d_out, int out_size, void* d_ws, size_t ws_size,
                              hipStream_t stream) {
    const int*   tokens = (const int*)d_in[0];
    const float* emb    = (const float*)d_in[1];
    const float* W      = (const float*)d_in[2];
    const float* b_l    = (const float*)d_in[3];
    const float* U      = (const float*)d_in[4];
    const float* b2     = (const float*)d_in[5];
    float* out = (float*)d_out;

    char* ws = (char*)d_ws;
    u16* Wf  = (u16*)(ws + WS_WF);
    u16* X   = (u16*)(ws + WS_X);
    u16* hs  = (u16*)(ws + WS_HS);

    // flags: 8 groups x 128 u32 (line-isolated) = 4096 B; boot: 288 u32 =
    // 1152 B (agent words in line 0; trial counters on private 128B lines).
    // Prefer workspace; fall back to d_out head if ws is exactly tight
    // (dead space during lstm_main; proj_kernel overwrites all of out).
    u32* bar;
    if (ws_size >= (size_t)WS_BAR + 4096 + 1152) bar = (u32*)(ws + WS_BAR);
    else                                         bar = (u32*)d_out;
    u32* boot = bar + 1024;

    hipMemsetAsync(bar, 0, 4096 + 1152, stream);
    prep_w<<<1280, 256, 0, stream>>>(W, Wf);
    prep_x<<<3840, 256, 0, stream>>>(tokens, emb, X);
    lstm_main<<<256, 512, 0, stream>>>(Wf, X, b_l, hs, bar, boot);
    proj_kernel<<<480, 256, 0, stream>>>(hs, U, b2, out);
}